// Round 14
// baseline (159.697 us; speedup 1.0000x reference)
//
#include <hip/hip_runtime.h>
#include <stdint.h>

#define BB 2
#define TT 2048
#define CCx 1024
#define HH 16
#define DD 64
#define MM (BB*TT)      // 4096
#define C3 (3*CCx)      // 3072

using u16 = unsigned short;
typedef __attribute__((ext_vector_type(8))) short short8;
typedef __attribute__((ext_vector_type(4))) float f32x4;
typedef __attribute__((ext_vector_type(16))) float f32x16;

__device__ __forceinline__ float bf2f(u16 u){
  union { unsigned int i; float f; } v; v.i = ((unsigned int)u) << 16; return v.f;
}
__device__ __forceinline__ u16 f2bf(float f){
  union { float f; unsigned int u; } v; v.f = f;
  unsigned int r = v.u + 0x7fffu + ((v.u >> 16) & 1u);
  return (u16)(r >> 16);
}

// 16x16x32: A-frag lane: row=lane&15, k=8*(lane>>4)+e; C/D: D[4*(lane>>4)+r][lane&15]
__device__ __forceinline__ f32x4 mfma16x16x32(short8 a, short8 b, f32x4 c){
  return __builtin_amdgcn_mfma_f32_16x16x32_bf16(a, b, c, 0, 0, 0);
}
// 32x32x16: A-frag lane: row=lane&31, k=8*(lane>>5)+e (analogy); C/D (verified):
// col=lane&31, row=(reg&3)+8*(reg>>2)+4*(lane>>5)
__device__ __forceinline__ f32x16 mfma32x32x16(short8 a, short8 b, f32x16 c){
  return __builtin_amdgcn_mfma_f32_32x32x16_bf16(a, b, c, 0, 0, 0);
}

typedef __attribute__((address_space(1))) unsigned int gu32;
typedef __attribute__((address_space(3))) unsigned int su32;
__device__ __forceinline__ void gload16(const void* g, void* l){
  __builtin_amdgcn_global_load_lds((gu32*)g, (su32*)l, 16, 0, 0);
}

// ---------------- x convert: f32 -> bf16 ----------------
__global__ __launch_bounds__(256) void cvt_x_k(const float* __restrict__ inv,
                                               u16* __restrict__ out, int n8){
  int i = blockIdx.x*256 + threadIdx.x;
  if (i >= n8) return;
  const float* p = inv + (size_t)i*8;
  float4 a = *(const float4*)p, b = *(const float4*)(p+4);
  short8 v;
  v[0]=(short)f2bf(a.x); v[1]=(short)f2bf(a.y); v[2]=(short)f2bf(a.z); v[3]=(short)f2bf(a.w);
  v[4]=(short)f2bf(b.x); v[5]=(short)f2bf(b.y); v[6]=(short)f2bf(b.z); v[7]=(short)f2bf(b.w);
  *(short8*)(out + (size_t)i*8) = v;
}

// ------- padded transpose+convert: in[R][Cc] f32 -> out[Cc][R] bf16 -----
__global__ __launch_bounds__(256) void transpose_cvt_k(const float* __restrict__ inv,
                                                       u16* __restrict__ out,
                                                       int R, int Cc){
  __shared__ u16 t[64][65];
  const int bx = blockIdx.x*64, by = blockIdx.y*64;
  const int tx = threadIdx.x & 63, ty = threadIdx.x >> 6;
  #pragma unroll
  for (int i = 0; i < 16; ++i){
    int r = ty + i*4;
    t[r][tx] = f2bf(inv[(size_t)(by+r)*Cc + bx+tx]);
  }
  __syncthreads();
  #pragma unroll
  for (int i = 0; i < 16; ++i){
    int r = ty + i*4;
    out[(size_t)(bx+r)*R + by+tx] = t[tx][r];
  }
}

// ---------------- GEMM (NT): C[M][N] = A[M][K]*BT[N][K]^T + bias ----------
// 128x128 tile, BK=64, 4 waves. XCD-bijective block swizzle (nwg % 8 == 0).
__global__ __launch_bounds__(256) void gemm_nt(const u16* __restrict__ A,
                                               const u16* __restrict__ BT,
                                               const float* __restrict__ bias,
                                               void* __restrict__ Cmat,
                                               int M, int N, int K, int of32){
  __shared__ u16 lA[128*64];
  __shared__ u16 lB[128*64];
  const int tid  = threadIdx.x;
  const int lane = tid & 63;
  const int wave = tid >> 6;
  // XCD swizzle: consecutive remapped ids stay on one XCD's L2
  const int nwg = gridDim.x * gridDim.y;
  const int lin = blockIdx.y * gridDim.x + blockIdx.x;
  const int wg  = (lin & 7) * (nwg >> 3) + (lin >> 3);
  const int bm = wg % gridDim.x, bn = wg / gridDim.x;
  const int wm = (wave >> 1) * 64;
  const int wn = (wave & 1) * 64;
  const int ln15 = lane & 15, g = lane >> 4;

  f32x4 acc[4][4];
  #pragma unroll
  for (int i = 0; i < 4; ++i)
    #pragma unroll
    for (int j = 0; j < 4; ++j) acc[i][j] = (f32x4){0.f,0.f,0.f,0.f};

  const int trow = tid >> 3;
  const int tc8s = (tid & 7) ^ (trow & 7);
  const size_t arow0 = (size_t)(bm*128) * K;
  const size_t brow0 = (size_t)(bn*128) * K;

  for (int k0 = 0; k0 < K; k0 += 64) {
    __syncthreads();
    #pragma unroll
    for (int c = 0; c < 4; ++c) {
      const int row = c*32 + trow;
      const size_t roff = (size_t)row*K + k0 + tc8s*8;
      gload16(A + arow0 + roff, (char*)lA + (c*256 + (wave<<6))*16);
      gload16(BT + brow0 + roff, (char*)lB + (c*256 + (wave<<6))*16);
    }
    asm volatile("s_waitcnt vmcnt(0)" ::: "memory");
    __syncthreads();

    short8 af[4][2], bfr[4][2];
    #pragma unroll
    for (int mf = 0; mf < 4; ++mf)
      #pragma unroll
      for (int kc = 0; kc < 2; ++kc) {
        const int r = wm + mf*16 + ln15;
        const int cb = (kc*64 + (g << 4)) ^ ((r & 7) << 4);
        af[mf][kc] = *(const short8*)((const char*)lA + r*128 + cb);
      }
    #pragma unroll
    for (int nf = 0; nf < 4; ++nf)
      #pragma unroll
      for (int kc = 0; kc < 2; ++kc) {
        const int r = wn + nf*16 + ln15;
        const int cb = (kc*64 + (g << 4)) ^ ((r & 7) << 4);
        bfr[nf][kc] = *(const short8*)((const char*)lB + r*128 + cb);
      }
    #pragma unroll
    for (int kc = 0; kc < 2; ++kc)
      #pragma unroll
      for (int mf = 0; mf < 4; ++mf)
        #pragma unroll
        for (int nf = 0; nf < 4; ++nf)
          acc[mf][nf] = mfma16x16x32(af[mf][kc], bfr[nf][kc], acc[mf][nf]);
  }

  #pragma unroll
  for (int nf = 0; nf < 4; ++nf) {
    const int col = bn*128 + wn + nf*16 + ln15;
    const float bv = bias[col];
    #pragma unroll
    for (int mf = 0; mf < 4; ++mf) {
      #pragma unroll
      for (int r = 0; r < 4; ++r) {
        const int rowg = bm*128 + wm + mf*16 + g*4 + r;
        const float v = acc[mf][nf][r] + bv;
        if (of32) ((float*)Cmat)[(size_t)rowg*N + col] = v;
        else      ((u16*)Cmat)[(size_t)rowg*N + col] = f2bf(v);
      }
    }
  }
}

// ------ causal flash attention (v7: 32x32 swapped-QK^T, in-register P) ------
// grid: (16, B*H); block 256 = 4 waves; block owns 128 q-rows (jq = 15 - bx,
// LPT). Wave owns 32 q-rows. Swapped QK^T: s = mfma32(K_frag, Q_frag) puts
// P-row lane-local (lane&31 = q). P -> pa via cvt_pk + shfl_xor(32), no LDS.
#define LOG2E_S 0.1803369f   // log2(e) * 0.125
__global__ __launch_bounds__(256, 2) void attn_k(const u16* __restrict__ qkv,
                                                 u16* __restrict__ y){
  __shared__ u16 kb[2][64*64];    // [key][d] 128B rows, 16B-chunk XOR swizzle (16KB)
  __shared__ u16 vb[2][64*64];    // [d][key] 128B rows, swz(d)=((d&7)+((d>>3)&7))&7 (16KB)
  const int tid  = threadIdx.x;
  const int lane = tid & 63;
  const int wave = tid >> 6;            // 0..3
  const int jq = 15 - blockIdx.x;       // LPT: heaviest first
  const int bh = blockIdx.y;
  const int b = bh >> 4, h = bh & 15;
  const int l31 = lane & 31;
  const int hw  = lane >> 5;            // half-wave
  const int q0w = jq*128 + wave*32;
  const int myq = q0w + l31;            // this lane's q-row
  const int ntw = 2*jq + (wave >> 1) + 1;   // tiles this wave computes
  const int nt  = 2*jq + 2;                 // staging loop length
  const size_t base = (size_t)b * TT * C3;

  // K staging: 2 gloads/thread; row krw & krw+32, chunk col (tid&7)^(krw&7)
  const int krw = tid >> 3;             // 0..31
  const int tc8 = (tid & 7) ^ (krw & 7);
  const u16* ksrc = qkv + base + CCx + h*DD + tc8*8 + (size_t)krw*C3;
  // V staging: thread owns keys (vkey, vkey+32), d = (tid&7)*8 .. +7
  const int vkey = tid >> 3, vc8 = tid & 7;
  const u16* vsrc = qkv + base + 2*CCx + h*DD + (size_t)vkey*C3 + vc8*8;

  // Q fragments (B-operand): lane: q-col = l31, d = 16*dk + 8*hw + e
  short8 qf[4];
  {
    const u16* qp = qkv + base + (size_t)myq*C3 + h*DD + hw*8;
    #pragma unroll
    for (int dk = 0; dk < 4; ++dk) qf[dk] = *(const short8*)(qp + 16*dk);
  }

  f32x16 o0, o1;
  #pragma unroll
  for (int i = 0; i < 16; ++i){ o0[i] = 0.f; o1[i] = 0.f; }
  float m = -1e30f, lsum = 0.f;

  short8 vr0, vr1;
  #define KSTAGE(curb, kv0v) do { \
    const u16* kp_ = ksrc + (size_t)(kv0v)*C3; \
    char* kd_ = (char*)kb + (curb)*8192 + wave*1024; \
    gload16(kp_, kd_); \
    gload16(kp_ + (size_t)32*C3, kd_ + 4096); \
  } while(0)
  #define VLOAD(kv0v) do { \
    vr0 = *(const short8*)(vsrc + (size_t)(kv0v)*C3); \
    vr1 = *(const short8*)(vsrc + (size_t)(kv0v + 32)*C3); \
  } while(0)
  #define VSTORE(curb) do { \
    char* vd_ = (char*)vb + (curb)*8192; \
    _Pragma("unroll") \
    for (int i = 0; i < 8; ++i){ \
      const int d_ = vc8*8 + i; \
      const int sw_ = (i + vc8) & 7; \
      *(u16*)(vd_ + d_*128 + (((vkey>>3) ^ sw_) << 4) + (vkey & 7)*2) = (u16)vr0[i]; \
      *(u16*)(vd_ + d_*128 + ((((vkey+32)>>3) ^ sw_) << 4) + (vkey & 7)*2) = (u16)vr1[i]; \
    } \
  } while(0)

  // prologue: stage tile 0
  KSTAGE(0, 0);
  VLOAD(0);
  asm volatile("s_waitcnt vmcnt(0)" ::: "memory");
  VSTORE(0);
  __syncthreads();

  int cur = 0;
  for (int t = 0; t < nt; ++t){
    const int kv0 = t*64;
    const bool hn = (t + 1 < nt);
    if (hn){ KSTAGE(cur^1, kv0 + 64); VLOAD(kv0 + 64); }

    if (t < ntw){
      // ---- swapped QK^T: s = K_tile x Q^T -> lane holds 32 keys of row myq
      const char* kbc = (const char*)kb + cur*8192;
      f32x16 s0, s1;
      #pragma unroll
      for (int i = 0; i < 16; ++i){ s0[i] = 0.f; s1[i] = 0.f; }
      #pragma unroll
      for (int dk = 0; dk < 4; ++dk){
        const int chunk = 2*dk + hw;
        const int r0 = l31, r1 = 32 + l31;
        short8 k0 = *(const short8*)(kbc + r0*128 + ((chunk ^ (r0 & 7)) << 4));
        short8 k1 = *(const short8*)(kbc + r1*128 + ((chunk ^ (r1 & 7)) << 4));
        s0 = mfma32x32x16(k0, qf[dk], s0);
        s1 = mfma32x32x16(k1, qf[dk], s1);
      }

      // ---- mask + per-row max (local + one half-swap) ----
      float tmax = -1e30f;
      #pragma unroll
      for (int r = 0; r < 16; ++r){
        const int key0 = kv0 + (r & 3) + 8*(r >> 2) + 4*hw;
        s0[r] = (key0      <= myq) ? s0[r] : -1e30f;
        s1[r] = (key0 + 32 <= myq) ? s1[r] : -1e30f;
        tmax = fmaxf(tmax, fmaxf(s0[r], s1[r]));
      }
      tmax = fmaxf(tmax, __shfl_xor(tmax, 32));

      // defer-max rescale (THR = 64 raw = 8 scaled)
      if (__any(tmax > m + 64.f)){
        const float nm = fmaxf(m, tmax);
        const float fac = exp2f((m - nm) * LOG2E_S);
        m = nm; lsum *= fac;
        #pragma unroll
        for (int r = 0; r < 16; ++r){
          const int qrow = (r & 3) + 8*(r >> 2) + 4*hw;
          const float fr = __shfl(fac, qrow);
          o0[r] *= fr; o1[r] *= fr;
        }
      }

      // ---- P = exp2(fma(s,LOG2E_S,-m')) + pack to bf16 pairs ----
      const float mscl = m * LOG2E_S;
      float rsum = 0.f;
      unsigned wpk0[2][4], wpk1[2][4];   // [kt][b]: pk(c0,c1), pk(c2,c3)
      #pragma unroll
      for (int bq = 0; bq < 4; ++bq){
        float p00 = exp2f(fmaf(s0[4*bq+0], LOG2E_S, -mscl));
        float p01 = exp2f(fmaf(s0[4*bq+1], LOG2E_S, -mscl));
        float p02 = exp2f(fmaf(s0[4*bq+2], LOG2E_S, -mscl));
        float p03 = exp2f(fmaf(s0[4*bq+3], LOG2E_S, -mscl));
        float p10 = exp2f(fmaf(s1[4*bq+0], LOG2E_S, -mscl));
        float p11 = exp2f(fmaf(s1[4*bq+1], LOG2E_S, -mscl));
        float p12 = exp2f(fmaf(s1[4*bq+2], LOG2E_S, -mscl));
        float p13 = exp2f(fmaf(s1[4*bq+3], LOG2E_S, -mscl));
        rsum += (p00+p01) + (p02+p03) + (p10+p11) + (p12+p13);
        asm("v_cvt_pk_bf16_f32 %0, %1, %2" : "=v"(wpk0[0][bq]) : "v"(p00), "v"(p01));
        asm("v_cvt_pk_bf16_f32 %0, %1, %2" : "=v"(wpk1[0][bq]) : "v"(p02), "v"(p03));
        asm("v_cvt_pk_bf16_f32 %0, %1, %2" : "=v"(wpk0[1][bq]) : "v"(p10), "v"(p11));
        asm("v_cvt_pk_bf16_f32 %0, %1, %2" : "=v"(wpk1[1][bq]) : "v"(p12), "v"(p13));
      }
      lsum += rsum + __shfl_xor(rsum, 32);

      // ---- assemble pa[4] (A-frags for PV) via half-swap exchange ----
      short8 pa[4];
      #pragma unroll
      for (int kt = 0; kt < 2; ++kt)
        #pragma unroll
        for (int j = 0; j < 2; ++j){
          const unsigned ownA  = hw ? wpk0[kt][2*j+1] : wpk0[kt][2*j];
          const unsigned ownB  = hw ? wpk1[kt][2*j+1] : wpk1[kt][2*j];
          const unsigned sendA = hw ? wpk0[kt][2*j]   : wpk0[kt][2*j+1];
          const unsigned sendB = hw ? wpk1[kt][2*j]   : wpk1[kt][2*j+1];
          const unsigned recvA = (unsigned)__shfl_xor((int)sendA, 32);
          const unsigned recvB = (unsigned)__shfl_xor((int)sendB, 32);
          union { unsigned u[4]; short8 s8; } pu;
          pu.u[0] = hw ? recvA : ownA;
          pu.u[1] = hw ? recvB : ownB;
          pu.u[2] = hw ? ownA : recvA;
          pu.u[3] = hw ? ownB : recvB;
          pa[2*kt + j] = pu.s8;
        }

      // ---- PV: O[32q x 64d] += P x V, V^T b-frags from vb[cur] ----
      const char* vbc = (const char*)vb + cur*8192;
      const int d0 = l31,      sw0 = ((d0 & 7) + ((d0 >> 3) & 7)) & 7;
      const int d1 = 32 + l31, sw1 = ((d1 & 7) + ((d1 >> 3) & 7)) & 7;
      #pragma unroll
      for (int ks = 0; ks < 4; ++ks){
        const int chunk = 2*ks + hw;
        short8 v0 = *(const short8*)(vbc + d0*128 + ((chunk ^ sw0) << 4));
        short8 v1 = *(const short8*)(vbc + d1*128 + ((chunk ^ sw1) << 4));
        o0 = mfma32x32x16(pa[ks], v0, o0);
        o1 = mfma32x32x16(pa[ks], v1, o1);
      }
    }

    if (hn){
      asm volatile("s_waitcnt vmcnt(0)" ::: "memory");
      VSTORE(cur^1);
    }
    __syncthreads();
    cur ^= 1;
  }

  // ---- normalize and store y (bf16): lane holds O[qrow][d=l31 / 32+l31] ----
  const float inv = 1.0f / lsum;
  #pragma unroll
  for (int r = 0; r < 16; ++r){
    const int qrow = (r & 3) + 8*(r >> 2) + 4*hw;
    const float ir = __shfl(inv, qrow);
    const size_t row = (size_t)(b*TT + q0w + qrow)*CCx + h*DD;
    y[row + l31]      = f2bf(o0[r] * ir);
    y[row + 32 + l31] = f2bf(o1[r] * ir);
  }
  #undef KSTAGE
  #undef VLOAD
  #undef VSTORE
}

extern "C" void kernel_launch(void* const* d_in, const int* in_sizes, int n_in,
                              void* d_out, int out_size, void* d_ws, size_t ws_size,
                              hipStream_t stream) {
  const float *x = nullptr, *w_attn = nullptr, *b_attn = nullptr,
              *w_proj = nullptr, *b_proj = nullptr;
  for (int i = 0; i < n_in; ++i) {
    switch (in_sizes[i]) {
      case MM*CCx:  x      = (const float*)d_in[i]; break;
      case C3*CCx:  w_attn = (const float*)d_in[i]; break;
      case C3:      b_attn = (const float*)d_in[i]; break;
      case CCx*CCx: w_proj = (const float*)d_in[i]; break;
      case CCx:     b_proj = (const float*)d_in[i]; break;
    }
  }
  float* out = (float*)d_out;

  char* ws = (char*)d_ws;
  u16* xb      = (u16*)ws;
  u16* wT_attn = xb + (size_t)MM*CCx;
  u16* wT_proj = wT_attn + (size_t)C3*CCx;
  u16* qkv     = wT_proj + (size_t)CCx*CCx;
  u16* ybuf    = qkv + (size_t)MM*C3;

  cvt_x_k<<<(MM*CCx/8 + 255)/256, 256, 0, stream>>>(x, xb, MM*CCx/8);
  transpose_cvt_k<<<dim3(C3/64, CCx/64), 256, 0, stream>>>(w_attn, wT_attn, CCx, C3);
  transpose_cvt_k<<<dim3(CCx/64, CCx/64), 256, 0, stream>>>(w_proj, wT_proj, CCx, CCx);
  gemm_nt<<<dim3(MM/128, C3/128), 256, 0, stream>>>(xb, wT_attn, b_attn, qkv, MM, C3, CCx, 0);
  attn_k<<<dim3(16, BB*HH), 256, 0, stream>>>(qkv, ybuf);
  gemm_nt<<<dim3(MM/128, CCx/128), 256, 0, stream>>>(ybuf, wT_proj, b_proj, out, MM, CCx, CCx, 1);
}

// Round 15
// 156.513 us; speedup vs baseline: 1.0203x; 1.0203x over previous
//
#include <hip/hip_runtime.h>
#include <stdint.h>

#define BB 2
#define TT 2048
#define CCx 1024
#define HH 16
#define DD 64
#define MM (BB*TT)      // 4096
#define C3 (3*CCx)      // 3072

using u16 = unsigned short;
typedef __attribute__((ext_vector_type(8))) short short8;
typedef __attribute__((ext_vector_type(4))) float f32x4;
typedef __attribute__((ext_vector_type(16))) float f32x16;

__device__ __forceinline__ float bf2f(u16 u){
  union { unsigned int i; float f; } v; v.i = ((unsigned int)u) << 16; return v.f;
}
__device__ __forceinline__ u16 f2bf(float f){
  union { float f; unsigned int u; } v; v.f = f;
  unsigned int r = v.u + 0x7fffu + ((v.u >> 16) & 1u);
  return (u16)(r >> 16);
}

// 16x16x32: A-frag lane: row=lane&15, k=8*(lane>>4)+e; C/D: D[4*(lane>>4)+r][lane&15]
__device__ __forceinline__ f32x4 mfma16x16x32(short8 a, short8 b, f32x4 c){
  return __builtin_amdgcn_mfma_f32_16x16x32_bf16(a, b, c, 0, 0, 0);
}
// 32x32x16: A-frag lane: row=lane&31, k=8*(lane>>5)+e (verified r14); C/D:
// col=lane&31, row=(reg&3)+8*(reg>>2)+4*(lane>>5)
__device__ __forceinline__ f32x16 mfma32x32x16(short8 a, short8 b, f32x16 c){
  return __builtin_amdgcn_mfma_f32_32x32x16_bf16(a, b, c, 0, 0, 0);
}

typedef __attribute__((address_space(1))) unsigned int gu32;
typedef __attribute__((address_space(3))) unsigned int su32;
__device__ __forceinline__ void gload16(const void* g, void* l){
  __builtin_amdgcn_global_load_lds((gu32*)g, (su32*)l, 16, 0, 0);
}

// ---------------- x convert: f32 -> bf16 ----------------
__global__ __launch_bounds__(256) void cvt_x_k(const float* __restrict__ inv,
                                               u16* __restrict__ out, int n8){
  int i = blockIdx.x*256 + threadIdx.x;
  if (i >= n8) return;
  const float* p = inv + (size_t)i*8;
  float4 a = *(const float4*)p, b = *(const float4*)(p+4);
  short8 v;
  v[0]=(short)f2bf(a.x); v[1]=(short)f2bf(a.y); v[2]=(short)f2bf(a.z); v[3]=(short)f2bf(a.w);
  v[4]=(short)f2bf(b.x); v[5]=(short)f2bf(b.y); v[6]=(short)f2bf(b.z); v[7]=(short)f2bf(b.w);
  *(short8*)(out + (size_t)i*8) = v;
}

// ------- padded transpose+convert: in[R][Cc] f32 -> out[Cc][R] bf16 -----
__global__ __launch_bounds__(256) void transpose_cvt_k(const float* __restrict__ inv,
                                                       u16* __restrict__ out,
                                                       int R, int Cc){
  __shared__ u16 t[64][65];
  const int bx = blockIdx.x*64, by = blockIdx.y*64;
  const int tx = threadIdx.x & 63, ty = threadIdx.x >> 6;
  #pragma unroll
  for (int i = 0; i < 16; ++i){
    int r = ty + i*4;
    t[r][tx] = f2bf(inv[(size_t)(by+r)*Cc + bx+tx]);
  }
  __syncthreads();
  #pragma unroll
  for (int i = 0; i < 16; ++i){
    int r = ty + i*4;
    out[(size_t)(bx+r)*R + by+tx] = t[tx][r];
  }
}

// ---------------- GEMM (NT): C[M][N] = A[M][K]*BT[N][K]^T + bias ----------
// 128x128 tile, BK=64, 4 waves. XCD-bijective block swizzle (nwg % 8 == 0).
__global__ __launch_bounds__(256) void gemm_nt(const u16* __restrict__ A,
                                               const u16* __restrict__ BT,
                                               const float* __restrict__ bias,
                                               void* __restrict__ Cmat,
                                               int M, int N, int K, int of32){
  __shared__ u16 lA[128*64];
  __shared__ u16 lB[128*64];
  const int tid  = threadIdx.x;
  const int lane = tid & 63;
  const int wave = tid >> 6;
  const int nwg = gridDim.x * gridDim.y;
  const int lin = blockIdx.y * gridDim.x + blockIdx.x;
  const int wg  = (lin & 7) * (nwg >> 3) + (lin >> 3);
  const int bm = wg % gridDim.x, bn = wg / gridDim.x;
  const int wm = (wave >> 1) * 64;
  const int wn = (wave & 1) * 64;
  const int ln15 = lane & 15, g = lane >> 4;

  f32x4 acc[4][4];
  #pragma unroll
  for (int i = 0; i < 4; ++i)
    #pragma unroll
    for (int j = 0; j < 4; ++j) acc[i][j] = (f32x4){0.f,0.f,0.f,0.f};

  const int trow = tid >> 3;
  const int tc8s = (tid & 7) ^ (trow & 7);
  const size_t arow0 = (size_t)(bm*128) * K;
  const size_t brow0 = (size_t)(bn*128) * K;

  for (int k0 = 0; k0 < K; k0 += 64) {
    __syncthreads();
    #pragma unroll
    for (int c = 0; c < 4; ++c) {
      const int row = c*32 + trow;
      const size_t roff = (size_t)row*K + k0 + tc8s*8;
      gload16(A + arow0 + roff, (char*)lA + (c*256 + (wave<<6))*16);
      gload16(BT + brow0 + roff, (char*)lB + (c*256 + (wave<<6))*16);
    }
    asm volatile("s_waitcnt vmcnt(0)" ::: "memory");
    __syncthreads();

    short8 af[4][2], bfr[4][2];
    #pragma unroll
    for (int mf = 0; mf < 4; ++mf)
      #pragma unroll
      for (int kc = 0; kc < 2; ++kc) {
        const int r = wm + mf*16 + ln15;
        const int cb = (kc*64 + (g << 4)) ^ ((r & 7) << 4);
        af[mf][kc] = *(const short8*)((const char*)lA + r*128 + cb);
      }
    #pragma unroll
    for (int nf = 0; nf < 4; ++nf)
      #pragma unroll
      for (int kc = 0; kc < 2; ++kc) {
        const int r = wn + nf*16 + ln15;
        const int cb = (kc*64 + (g << 4)) ^ ((r & 7) << 4);
        bfr[nf][kc] = *(const short8*)((const char*)lB + r*128 + cb);
      }
    #pragma unroll
    for (int kc = 0; kc < 2; ++kc)
      #pragma unroll
      for (int mf = 0; mf < 4; ++mf)
        #pragma unroll
        for (int nf = 0; nf < 4; ++nf)
          acc[mf][nf] = mfma16x16x32(af[mf][kc], bfr[nf][kc], acc[mf][nf]);
  }

  #pragma unroll
  for (int nf = 0; nf < 4; ++nf) {
    const int col = bn*128 + wn + nf*16 + ln15;
    const float bv = bias[col];
    #pragma unroll
    for (int mf = 0; mf < 4; ++mf) {
      #pragma unroll
      for (int r = 0; r < 4; ++r) {
        const int rowg = bm*128 + wm + mf*16 + g*4 + r;
        const float v = acc[mf][nf][r] + bv;
        if (of32) ((float*)Cmat)[(size_t)rowg*N + col] = v;
        else      ((u16*)Cmat)[(size_t)rowg*N + col] = f2bf(v);
      }
    }
  }
}

// -- causal flash attention (v8: 32x32 swapped-QK^T + paired tiles in block) --
// grid: (16, B*H); block 256 = 4 waves. Waves {0,1} own 64-row q-tile a,
// waves {2,3} own tile 31-a (a = bx<8 ? bx : 23-bx: per-XCD staging sum = 49
// uniform, compute 66/block uniform, heavy-first). Wave owns 32 q-rows;
// swapped QK^T puts P lane-local; P->pa via cvt_pk + shfl_xor(32), no P LDS.
#define LOG2E_S 0.1803369f   // log2(e) * 0.125
__global__ __launch_bounds__(256, 2) void attn_k(const u16* __restrict__ qkv,
                                                 u16* __restrict__ y){
  __shared__ u16 kb[2][64*64];    // [key][d] 128B rows, 16B-chunk XOR swizzle (16KB)
  __shared__ u16 vb[2][64*64];    // [d][key] 128B rows, swz(d)=((d&7)+((d>>3)&7))&7 (16KB)
  const int tid  = threadIdx.x;
  const int lane = tid & 63;
  const int wave = tid >> 6;            // 0..3
  const int bx = blockIdx.x;
  const int a  = (bx < 8) ? bx : (23 - bx);   // XCD-uniform pairing, heavy first
  const int bh = blockIdx.y;
  const int b = bh >> 4, h = bh & 15;
  const int l31 = lane & 31;
  const int hw  = lane >> 5;            // half-wave
  const int sub = wave >> 1;            // 0: tile a, 1: tile 31-a
  const int wq  = wave & 1;
  const int jt  = sub ? (31 - a) : a;   // this wave's 64-row q-tile
  const int q0w = jt*64 + wq*32;
  const int myq = q0w + l31;            // this lane's q-row
  const int ntw = sub ? (32 - a) : (a + 1);   // tiles this wave computes
  const int nt  = 32 - a;                      // staging loop length
  const size_t base = (size_t)b * TT * C3;

  // K staging: 2 gloads/thread; rows krw & krw+32, chunk col (tid&7)^(krw&7)
  const int krw = tid >> 3;             // 0..31
  const int tc8 = (tid & 7) ^ (krw & 7);
  const u16* ksrc = qkv + base + CCx + h*DD + tc8*8 + (size_t)krw*C3;
  // V staging: thread owns keys (vkey, vkey+32), d = (tid&7)*8 .. +7
  const int vkey = tid >> 3, vc8 = tid & 7;
  const u16* vsrc = qkv + base + 2*CCx + h*DD + (size_t)vkey*C3 + vc8*8;

  // Q fragments (B-operand): lane: q-col = l31, d = 16*dk + 8*hw + e
  short8 qf[4];
  {
    const u16* qp = qkv + base + (size_t)myq*C3 + h*DD + hw*8;
    #pragma unroll
    for (int dk = 0; dk < 4; ++dk) qf[dk] = *(const short8*)(qp + 16*dk);
  }

  f32x16 o0, o1;
  #pragma unroll
  for (int i = 0; i < 16; ++i){ o0[i] = 0.f; o1[i] = 0.f; }
  float m = -1e30f, lsum = 0.f;

  short8 vr0, vr1;
  #define KSTAGE(curb, kv0v) do { \
    const u16* kp_ = ksrc + (size_t)(kv0v)*C3; \
    char* kd_ = (char*)kb + (curb)*8192 + wave*1024; \
    gload16(kp_, kd_); \
    gload16(kp_ + (size_t)32*C3, kd_ + 4096); \
  } while(0)
  #define VLOAD(kv0v) do { \
    vr0 = *(const short8*)(vsrc + (size_t)(kv0v)*C3); \
    vr1 = *(const short8*)(vsrc + (size_t)(kv0v + 32)*C3); \
  } while(0)
  #define VSTORE(curb) do { \
    char* vd_ = (char*)vb + (curb)*8192; \
    _Pragma("unroll") \
    for (int i = 0; i < 8; ++i){ \
      const int d_ = vc8*8 + i; \
      const int sw_ = (i + vc8) & 7; \
      *(u16*)(vd_ + d_*128 + (((vkey>>3) ^ sw_) << 4) + (vkey & 7)*2) = (u16)vr0[i]; \
      *(u16*)(vd_ + d_*128 + ((((vkey+32)>>3) ^ sw_) << 4) + (vkey & 7)*2) = (u16)vr1[i]; \
    } \
  } while(0)

  // prologue: stage tile 0
  KSTAGE(0, 0);
  VLOAD(0);
  asm volatile("s_waitcnt vmcnt(0)" ::: "memory");
  VSTORE(0);
  __syncthreads();

  int cur = 0;
  for (int t = 0; t < nt; ++t){
    const int kv0 = t*64;
    const bool hn = (t + 1 < nt);
    if (hn){ KSTAGE(cur^1, kv0 + 64); VLOAD(kv0 + 64); }

    if (t < ntw){
      // ---- swapped QK^T: s = K_tile x Q^T -> lane holds 32 keys of row myq
      const char* kbc = (const char*)kb + cur*8192;
      f32x16 s0, s1;
      #pragma unroll
      for (int i = 0; i < 16; ++i){ s0[i] = 0.f; s1[i] = 0.f; }
      #pragma unroll
      for (int dk = 0; dk < 4; ++dk){
        const int chunk = 2*dk + hw;
        const int r0 = l31, r1 = 32 + l31;
        short8 k0 = *(const short8*)(kbc + r0*128 + ((chunk ^ (r0 & 7)) << 4));
        short8 k1 = *(const short8*)(kbc + r1*128 + ((chunk ^ (r1 & 7)) << 4));
        s0 = mfma32x32x16(k0, qf[dk], s0);
        s1 = mfma32x32x16(k1, qf[dk], s1);
      }

      // ---- mask + per-row max (local + one half-swap) ----
      float tmax = -1e30f;
      #pragma unroll
      for (int r = 0; r < 16; ++r){
        const int key0 = kv0 + (r & 3) + 8*(r >> 2) + 4*hw;
        s0[r] = (key0      <= myq) ? s0[r] : -1e30f;
        s1[r] = (key0 + 32 <= myq) ? s1[r] : -1e30f;
        tmax = fmaxf(tmax, fmaxf(s0[r], s1[r]));
      }
      tmax = fmaxf(tmax, __shfl_xor(tmax, 32));

      // defer-max rescale (THR = 64 raw = 8 scaled)
      if (__any(tmax > m + 64.f)){
        const float nm = fmaxf(m, tmax);
        const float fac = exp2f((m - nm) * LOG2E_S);
        m = nm; lsum *= fac;
        #pragma unroll
        for (int r = 0; r < 16; ++r){
          const int qrow = (r & 3) + 8*(r >> 2) + 4*hw;
          const float fr = __shfl(fac, qrow);
          o0[r] *= fr; o1[r] *= fr;
        }
      }

      // ---- P = exp2(fma(s,LOG2E_S,-m')) + pack to bf16 pairs ----
      const float mscl = m * LOG2E_S;
      float rsum = 0.f;
      unsigned wpk0[2][4], wpk1[2][4];
      #pragma unroll
      for (int bq = 0; bq < 4; ++bq){
        float p00 = exp2f(fmaf(s0[4*bq+0], LOG2E_S, -mscl));
        float p01 = exp2f(fmaf(s0[4*bq+1], LOG2E_S, -mscl));
        float p02 = exp2f(fmaf(s0[4*bq+2], LOG2E_S, -mscl));
        float p03 = exp2f(fmaf(s0[4*bq+3], LOG2E_S, -mscl));
        float p10 = exp2f(fmaf(s1[4*bq+0], LOG2E_S, -mscl));
        float p11 = exp2f(fmaf(s1[4*bq+1], LOG2E_S, -mscl));
        float p12 = exp2f(fmaf(s1[4*bq+2], LOG2E_S, -mscl));
        float p13 = exp2f(fmaf(s1[4*bq+3], LOG2E_S, -mscl));
        rsum += (p00+p01) + (p02+p03) + (p10+p11) + (p12+p13);
        asm("v_cvt_pk_bf16_f32 %0, %1, %2" : "=v"(wpk0[0][bq]) : "v"(p00), "v"(p01));
        asm("v_cvt_pk_bf16_f32 %0, %1, %2" : "=v"(wpk1[0][bq]) : "v"(p02), "v"(p03));
        asm("v_cvt_pk_bf16_f32 %0, %1, %2" : "=v"(wpk0[1][bq]) : "v"(p10), "v"(p11));
        asm("v_cvt_pk_bf16_f32 %0, %1, %2" : "=v"(wpk1[1][bq]) : "v"(p12), "v"(p13));
      }
      lsum += rsum + __shfl_xor(rsum, 32);

      // ---- assemble pa[4] (A-frags for PV) via half-swap exchange ----
      short8 pa[4];
      #pragma unroll
      for (int kt = 0; kt < 2; ++kt)
        #pragma unroll
        for (int j = 0; j < 2; ++j){
          const unsigned ownA  = hw ? wpk0[kt][2*j+1] : wpk0[kt][2*j];
          const unsigned ownB  = hw ? wpk1[kt][2*j+1] : wpk1[kt][2*j];
          const unsigned sendA = hw ? wpk0[kt][2*j]   : wpk0[kt][2*j+1];
          const unsigned sendB = hw ? wpk1[kt][2*j]   : wpk1[kt][2*j+1];
          const unsigned recvA = (unsigned)__shfl_xor((int)sendA, 32);
          const unsigned recvB = (unsigned)__shfl_xor((int)sendB, 32);
          union { unsigned u[4]; short8 s8; } pu;
          pu.u[0] = hw ? recvA : ownA;
          pu.u[1] = hw ? recvB : ownB;
          pu.u[2] = hw ? ownA : recvA;
          pu.u[3] = hw ? ownB : recvB;
          pa[2*kt + j] = pu.s8;
        }

      // ---- PV: O[32q x 64d] += P x V, V^T b-frags from vb[cur] ----
      const char* vbc = (const char*)vb + cur*8192;
      const int d0 = l31,      sw0 = ((d0 & 7) + ((d0 >> 3) & 7)) & 7;
      const int d1 = 32 + l31, sw1 = ((d1 & 7) + ((d1 >> 3) & 7)) & 7;
      #pragma unroll
      for (int ks = 0; ks < 4; ++ks){
        const int chunk = 2*ks + hw;
        short8 v0 = *(const short8*)(vbc + d0*128 + ((chunk ^ sw0) << 4));
        short8 v1 = *(const short8*)(vbc + d1*128 + ((chunk ^ sw1) << 4));
        o0 = mfma32x32x16(pa[ks], v0, o0);
        o1 = mfma32x32x16(pa[ks], v1, o1);
      }
    }

    if (hn){
      asm volatile("s_waitcnt vmcnt(0)" ::: "memory");
      VSTORE(cur^1);
    }
    __syncthreads();
    cur ^= 1;
  }

  // ---- normalize and store y (bf16): lane holds O[qrow][d=l31 / 32+l31] ----
  const float inv = 1.0f / lsum;
  #pragma unroll
  for (int r = 0; r < 16; ++r){
    const int qrow = (r & 3) + 8*(r >> 2) + 4*hw;
    const float ir = __shfl(inv, qrow);
    const size_t row = (size_t)(b*TT + q0w + qrow)*CCx + h*DD;
    y[row + l31]      = f2bf(o0[r] * ir);
    y[row + 32 + l31] = f2bf(o1[r] * ir);
  }
  #undef KSTAGE
  #undef VLOAD
  #undef VSTORE
}

extern "C" void kernel_launch(void* const* d_in, const int* in_sizes, int n_in,
                              void* d_out, int out_size, void* d_ws, size_t ws_size,
                              hipStream_t stream) {
  const float *x = nullptr, *w_attn = nullptr, *b_attn = nullptr,
              *w_proj = nullptr, *b_proj = nullptr;
  for (int i = 0; i < n_in; ++i) {
    switch (in_sizes[i]) {
      case MM*CCx:  x      = (const float*)d_in[i]; break;
      case C3*CCx:  w_attn = (const float*)d_in[i]; break;
      case C3:      b_attn = (const float*)d_in[i]; break;
      case CCx*CCx: w_proj = (const float*)d_in[i]; break;
      case CCx:     b_proj = (const float*)d_in[i]; break;
    }
  }
  float* out = (float*)d_out;

  char* ws = (char*)d_ws;
  u16* xb      = (u16*)ws;
  u16* wT_attn = xb + (size_t)MM*CCx;
  u16* wT_proj = wT_attn + (size_t)C3*CCx;
  u16* qkv     = wT_proj + (size_t)CCx*CCx;
  u16* ybuf    = qkv + (size_t)MM*C3;

  cvt_x_k<<<(MM*CCx/8 + 255)/256, 256, 0, stream>>>(x, xb, MM*CCx/8);
  transpose_cvt_k<<<dim3(C3/64, CCx/64), 256, 0, stream>>>(w_attn, wT_attn, CCx, C3);
  transpose_cvt_k<<<dim3(CCx/64, CCx/64), 256, 0, stream>>>(w_proj, wT_proj, CCx, CCx);
  gemm_nt<<<dim3(MM/128, C3/128), 256, 0, stream>>>(xb, wT_attn, b_attn, qkv, MM, C3, CCx, 0);
  attn_k<<<dim3(16, BB*HH), 256, 0, stream>>>(qkv, ybuf);
  gemm_nt<<<dim3(MM/128, CCx/128), 256, 0, stream>>>(ybuf, wT_proj, b_proj, out, MM, CCx, CCx, 1);
}